// Round 9
// baseline (690.683 us; speedup 1.0000x reference)
//
#include <hip/hip_runtime.h>

#define B_IMG 8
#define D_DIM 32
#define NPIX 262144          // 512*512
#define K_CL 16
#define CHUNK 2048
#define CHUNKS (NPIX / CHUNK)    // 128
#define F4_D (NPIX / 4)          // float4 stride between channels

typedef float f4 __attribute__((ext_vector_type(4)));   // clang vector: valid for nontemporal builtins

__device__ __forceinline__ float wave_sum(float v) {
#pragma unroll
  for (int off = 32; off > 0; off >>= 1) v += __shfl_xor(v, off, 64);
  return v;
}

// ---------------- Pass A: counts + per-(k,d) sums via ds_add bins ----------------
__global__ __launch_bounds__(256) void k_sums(const float* __restrict__ emb,
                                              const int* __restrict__ gt,
                                              float* __restrict__ sums,
                                              float* __restrict__ counts) {
  __shared__ float bins[K_CL][D_DIM][16];   // 32 KB
  __shared__ float cnt[K_CL][16];           // 1 KB
  const int tid = threadIdx.x;
  const int b = blockIdx.x >> 7;            // CHUNKS == 128
  const int chunk = blockIdx.x & (CHUNKS - 1);
  const int base = chunk * CHUNK;
  const int col = tid & 15;

  // zero LDS
  {
    f4* bz = (f4*)bins;                     // 2048 vectors
#pragma unroll
    for (int i = 0; i < 8; i++) bz[tid + (i << 8)] = (f4)0.f;
    if (tid < 64) ((f4*)cnt)[tid] = (f4)0.f;
  }

  int lb[8];
  {
    const int4* lp = (const int4*)(gt + (size_t)b * NPIX + base);
    int4 a0 = lp[tid];
    int4 a1 = lp[256 + tid];
    lb[0] = a0.x; lb[1] = a0.y; lb[2] = a0.z; lb[3] = a0.w;
    lb[4] = a1.x; lb[5] = a1.y; lb[6] = a1.z; lb[7] = a1.w;
  }
  __syncthreads();

#pragma unroll
  for (int j = 0; j < 8; j++) atomicAdd(&cnt[lb[j]][col], 1.0f);

  for (int g = 0; g < 8; g++) {             // channel groups of 4
    const f4* eb = (const f4*)(emb + ((size_t)b * D_DIM + g * 4) * NPIX + base);
#pragma unroll
    for (int h = 0; h < 2; h++) {           // two vector batches of 4 px
      f4 v0 = __builtin_nontemporal_load(&eb[(size_t)0 * F4_D + tid + (h << 8)]);
      f4 v1 = __builtin_nontemporal_load(&eb[(size_t)1 * F4_D + tid + (h << 8)]);
      f4 v2 = __builtin_nontemporal_load(&eb[(size_t)2 * F4_D + tid + (h << 8)]);
      f4 v3 = __builtin_nontemporal_load(&eb[(size_t)3 * F4_D + tid + (h << 8)]);
#pragma unroll
      for (int c = 0; c < 4; c++) {
        const int l = lb[(h << 2) | c];
        atomicAdd(&bins[l][g * 4 + 0][col], v0[c]);
        atomicAdd(&bins[l][g * 4 + 1][col], v1[c]);
        atomicAdd(&bins[l][g * 4 + 2][col], v2[c]);
        atomicAdd(&bins[l][g * 4 + 3][col], v3[c]);
      }
    }
  }
  __syncthreads();

  // single flush: 512 (k,d) pairs, 2 per thread; no shuffle chains
#pragma unroll
  for (int p0 = 0; p0 < 2; p0++) {
    const int p = tid + (p0 << 8);          // p = k*32 + d
    const f4* r = (const f4*)bins[p >> 5][p & 31];
    f4 s0 = r[0], s1 = r[1], s2 = r[2], s3 = r[3];
    const float tot = (s0[0] + s0[1] + s0[2] + s0[3]) + (s1[0] + s1[1] + s1[2] + s1[3]) +
                      (s2[0] + s2[1] + s2[2] + s2[3]) + (s3[0] + s3[1] + s3[2] + s3[3]);
    unsafeAtomicAdd(&sums[(size_t)b * K_CL * D_DIM + p], tot);
  }
  if (tid < K_CL) {
    const f4* r = (const f4*)cnt[tid];
    f4 s0 = r[0], s1 = r[1], s2 = r[2], s3 = r[3];
    const float tot = (s0[0] + s0[1] + s0[2] + s0[3]) + (s1[0] + s1[1] + s1[2] + s1[3]) +
                      (s2[0] + s2[1] + s2[2] + s2[3]) + (s3[0] + s3[1] + s3[2] + s3[3]);
    unsafeAtomicAdd(&counts[b * K_CL + tid], tot);
  }
}

// ---------------- k_means: means, msq, distance+reg loss (8 blocks) ----------------
__global__ __launch_bounds__(256) void k_means(const float* __restrict__ sums,
                                               const float* __restrict__ counts,
                                               float* __restrict__ mt,       // [b][d][k]
                                               float* __restrict__ msq_g,    // [b][k]
                                               float* __restrict__ dist_reg) {
  __shared__ float mm[K_CL][33];
  __shared__ float msq_s[K_CL];
  __shared__ float red4[4];
  const int b = blockIdx.x;
  const int t = threadIdx.x;

#pragma unroll
  for (int e0 = 0; e0 < 2; e0++) {
    const int e = t + (e0 << 8);            // e = k*32 + d
    const int k = e >> 5, d = e & 31;
    const float c = fmaxf(counts[b * K_CL + k], 1.0f);
    const float m = sums[(size_t)b * K_CL * D_DIM + e] / c;
    mm[k][d] = m;
    mt[(size_t)b * D_DIM * K_CL + d * K_CL + k] = m;   // transposed for k_var
  }
  __syncthreads();
  if (t < K_CL) {
    float s = 0.f;
#pragma unroll
    for (int d = 0; d < D_DIM; d++) { const float m = mm[t][d]; s = fmaf(m, m, s); }
    msq_s[t] = s;
    msq_g[b * K_CL + t] = s;
  }
  __syncthreads();

  const int i = t >> 4, j = t & 15;
  float sq = 0.f;
#pragma unroll
  for (int d = 0; d < D_DIM; d++) {
    const float df = mm[i][d] - mm[j][d];
    sq = fmaf(df, df, sq);
  }
  float contrib = 0.f;
  if (i < j) {
    const float h = fmaxf(3.0f - sqrtf(sq), 0.0f);     // 2*DIST_THETA
    contrib = h * h;
  }
  const float tot = wave_sum(contrib);
  if ((t & 63) == 0) red4[t >> 6] = tot;
  __syncthreads();
  if (t == 0) {
    const float dist = (red4[0] + red4[1] + red4[2] + red4[3]) * (1.0f / 240.0f);
    float reg = 0.f;
#pragma unroll
    for (int k = 0; k < K_CL; k++) reg += sqrtf(msq_s[k]);
    dist_reg[b] = dist + 0.001f * (reg * (1.0f / 16.0f));
  }
}

// ---------------- Pass C: variance loss, 2-deep prefetched ----------------
__global__ __launch_bounds__(256) void k_var(const float* __restrict__ emb,
                                             const int* __restrict__ gt,
                                             const float* __restrict__ mt,
                                             const float* __restrict__ msq_g,
                                             float* __restrict__ var_sums) {
  __shared__ float tm[D_DIM][K_CL];         // 2*mean, [d][k]
  __shared__ float msq[K_CL];
  __shared__ float vacc[K_CL][16];
  const int tid = threadIdx.x;
  const int b = blockIdx.x >> 7;
  const int chunk = blockIdx.x & (CHUNKS - 1);
  const int base = chunk * CHUNK;
  const int col = tid & 15;

#pragma unroll
  for (int e0 = 0; e0 < 2; e0++) {
    const int e = tid + (e0 << 8);
    ((float*)tm)[e] = 2.0f * mt[(size_t)b * D_DIM * K_CL + e];
  }
  if (tid < K_CL) msq[tid] = msq_g[b * K_CL + tid];
  ((float*)vacc)[tid] = 0.f;

  int lb[8];
  {
    const int4* lp = (const int4*)(gt + (size_t)b * NPIX + base);
    int4 a0 = lp[tid];
    int4 a1 = lp[256 + tid];
    lb[0] = a0.x; lb[1] = a0.y; lb[2] = a0.z; lb[3] = a0.w;
    lb[4] = a1.x; lb[5] = a1.y; lb[6] = a1.z; lb[7] = a1.w;
  }
  __syncthreads();

  float a[8] = {0.f, 0.f, 0.f, 0.f, 0.f, 0.f, 0.f, 0.f};
  const f4* P = (const f4*)(emb + (size_t)b * D_DIM * NPIX + base);

  // software pipeline, depth 2 (named buffers, static indexing)
  f4 A0 = __builtin_nontemporal_load(&P[tid]);
  f4 B0 = __builtin_nontemporal_load(&P[256 + tid]);
  f4 A1 = __builtin_nontemporal_load(&P[(size_t)F4_D + tid]);
  f4 B1 = __builtin_nontemporal_load(&P[(size_t)F4_D + 256 + tid]);

  for (int d = 0; d < D_DIM; d += 2) {
    {
      const float* td = tm[d];
#pragma unroll
      for (int j = 0; j < 4; j++) {
        const float x = A0[j];
        a[j] = fmaf(x, x - td[lb[j]], a[j]);
      }
#pragma unroll
      for (int j = 0; j < 4; j++) {
        const float x = B0[j];
        a[4 + j] = fmaf(x, x - td[lb[4 + j]], a[4 + j]);
      }
      const int dn = (d + 2) & 31;          // wrap: last 2 loads are discarded re-reads
      A0 = __builtin_nontemporal_load(&P[(size_t)dn * F4_D + tid]);
      B0 = __builtin_nontemporal_load(&P[(size_t)dn * F4_D + 256 + tid]);
    }
    {
      const float* te = tm[d + 1];
#pragma unroll
      for (int j = 0; j < 4; j++) {
        const float x = A1[j];
        a[j] = fmaf(x, x - te[lb[j]], a[j]);
      }
#pragma unroll
      for (int j = 0; j < 4; j++) {
        const float x = B1[j];
        a[4 + j] = fmaf(x, x - te[lb[4 + j]], a[4 + j]);
      }
      const int dm = (d + 3) & 31;
      A1 = __builtin_nontemporal_load(&P[(size_t)dm * F4_D + tid]);
      B1 = __builtin_nontemporal_load(&P[(size_t)dm * F4_D + 256 + tid]);
    }
  }

#pragma unroll
  for (int j = 0; j < 8; j++) {
    const float d2 = a[j] + msq[lb[j]];
    const float dd = sqrtf(fmaxf(d2, 0.f));
    const float h = fmaxf(dd - 0.5f, 0.f);  // VAR_THETA
    atomicAdd(&vacc[lb[j]][col], h * h);
  }
  __syncthreads();
  if (tid < K_CL) {
    const f4* r = (const f4*)vacc[tid];
    f4 s0 = r[0], s1 = r[1], s2 = r[2], s3 = r[3];
    const float tot = (s0[0] + s0[1] + s0[2] + s0[3]) + (s1[0] + s1[1] + s1[2] + s1[3]) +
                      (s2[0] + s2[1] + s2[2] + s2[3]) + (s3[0] + s3[1] + s3[2] + s3[3]);
    unsafeAtomicAdd(&var_sums[b * K_CL + tid], tot);
  }
}

// ---------------- Final combine ----------------
__global__ __launch_bounds__(128) void k_final(const float* __restrict__ counts,
                                               const float* __restrict__ var_sums,
                                               const float* __restrict__ dist_reg,
                                               float* __restrict__ out) {
  const int t = threadIdx.x;                // t = b*16 + k
  float pc = 0.f;
  if (t < B_IMG * K_CL) pc = var_sums[t] / fmaxf(counts[t], 1.0f);
#pragma unroll
  for (int off = 8; off > 0; off >>= 1) pc += __shfl_xor(pc, off, 64);
  __shared__ float lbl[B_IMG];
  if (t < B_IMG * K_CL && (t & 15) == 0) {
    const int b = t >> 4;
    lbl[b] = pc * (1.0f / 16.0f) + dist_reg[b];
  }
  __syncthreads();
  if (t == 0) {
    float s = 0.f;
#pragma unroll
    for (int b = 0; b < B_IMG; b++) s += lbl[b];
    out[0] = s * (1.0f / B_IMG);
  }
}

extern "C" void kernel_launch(void* const* d_in, const int* in_sizes, int n_in,
                              void* d_out, int out_size, void* d_ws, size_t ws_size,
                              hipStream_t stream) {
  const float* emb = (const float*)d_in[0];
  const int* gt = (const int*)d_in[1];
  float* out = (float*)d_out;

  float* sums = (float*)d_ws;                            // 4096
  float* counts = sums + B_IMG * K_CL * D_DIM;           // 128
  float* var_sums = counts + B_IMG * K_CL;               // 128
  float* dist_reg = var_sums + B_IMG * K_CL;             // 8
  float* mt = dist_reg + B_IMG;                          // 4096 (written fully by k_means)
  float* msq_g = mt + B_IMG * D_DIM * K_CL;              // 128 (written fully by k_means)

  const size_t zero_floats = B_IMG * K_CL * D_DIM + 2 * B_IMG * K_CL + B_IMG;
  (void)hipMemsetAsync(d_ws, 0, zero_floats * sizeof(float), stream);

  k_sums<<<dim3(B_IMG * CHUNKS), dim3(256), 0, stream>>>(emb, gt, sums, counts);
  k_means<<<dim3(B_IMG), dim3(256), 0, stream>>>(sums, counts, mt, msq_g, dist_reg);
  k_var<<<dim3(B_IMG * CHUNKS), dim3(256), 0, stream>>>(emb, gt, mt, msq_g, var_sums);
  k_final<<<dim3(1), dim3(128), 0, stream>>>(counts, var_sums, dist_reg, out);
}